// Round 2
// baseline (795.886 us; speedup 1.0000x reference)
//
#include <hip/hip_runtime.h>
#include <math.h>

#define N_NODES 100000
#define N_EDGES 3200000
#define F_IN    512
#define HID     16

#define ROWS_PER_CHUNK 8
#define NCHUNK (N_NODES / ROWS_PER_CHUNK)   // 12500 exactly
#define GEMM1_BLOCKS 512

typedef const __attribute__((address_space(1))) void g_void;
typedef __attribute__((address_space(3))) void l_void;

// ---------------------------------------------------------------------------
// Degree count: deg[d] += 1 per edge (self-loop folded in later as +1)
__global__ void k_deg(const int* __restrict__ dst, float* __restrict__ deg) {
    int e = blockIdx.x * blockDim.x + threadIdx.x;
    if (e < N_EDGES) atomicAdd(&deg[dst[e]], 1.0f);
}

__global__ void k_dinv(const float* __restrict__ deg, float* __restrict__ dinv) {
    int i = blockIdx.x * blockDim.x + threadIdx.x;
    if (i < N_NODES) dinv[i] = rsqrtf(deg[i] + 1.0f);  // +1 = self-loop
}

// ---------------------------------------------------------------------------
// GEMM1: hs1[i][k] = (sum_f x[i][f] * W1[f][k]) * dinv[i];  acc1 = hs1 (self-loop init)
// 2-phase global_load_lds pipeline: stage 8 rows (16KB) into LDS double-buffer,
// counted vmcnt(4) + raw s_barrier (NO __syncthreads -> no vmcnt(0) drain).
// Lane layout: q = lane>>4 owns f-quarter [q*128, q*128+128); k = lane&15.
// W1 slice (128 floats) register-resident, compile-time indexed.
__global__ __launch_bounds__(256, 2)
void k_gemm1(const float* __restrict__ x, const float* __restrict__ W1,
             const float* __restrict__ dinv, float* __restrict__ hs1,
             float* __restrict__ acc1) {
    __shared__ float xs[2 * ROWS_PER_CHUNK * F_IN];   // 2 x 16KB
    const int tid  = threadIdx.x;
    const int lane = tid & 63;
    const int wib  = tid >> 6;     // wave in block (4 waves)
    const int q    = lane >> 4;    // f-quarter
    const int k    = lane & 15;    // output column

    // Preload W1[f][k] for f = q*128 + j  (stride HID floats)
    float w[128];
    {
        const float* wp = W1 + (size_t)(q * 128) * HID + k;
#pragma unroll
        for (int j = 0; j < 128; ++j) w[j] = wp[(size_t)j * HID];
    }

    int chunk = blockIdx.x;
    int par = 0;
    // prologue: stage chunk into buf0. Each wave: 4 x global_load_lds(16B)
    {
        const float* gb = x + (size_t)chunk * (ROWS_PER_CHUNK * F_IN);
#pragma unroll
        for (int j = 0; j < 4; ++j) {
            int cidx = j * 4 + wib;                       // 1KB sub-chunk id
            __builtin_amdgcn_global_load_lds(
                (g_void*)(gb + cidx * 256 + lane * 4),    // per-lane global src
                (l_void*)(xs + cidx * 256),               // wave-uniform LDS base
                16, 0, 0);
        }
    }

    for (; chunk < NCHUNK; chunk += GEMM1_BLOCKS) {
        const int nxt = chunk + GEMM1_BLOCKS;
        const bool more = (nxt < NCHUNK);
        if (more) {
            const float* gb = x + (size_t)nxt * (ROWS_PER_CHUNK * F_IN);
            float* lb = xs + (par ^ 1) * (ROWS_PER_CHUNK * F_IN);
#pragma unroll
            for (int j = 0; j < 4; ++j) {
                int cidx = j * 4 + wib;
                __builtin_amdgcn_global_load_lds(
                    (g_void*)(gb + cidx * 256 + lane * 4),
                    (l_void*)(lb + cidx * 256),
                    16, 0, 0);
            }
            asm volatile("s_waitcnt vmcnt(4)" ::: "memory");  // current buf landed; 4 new in flight
        } else {
            asm volatile("s_waitcnt vmcnt(0)" ::: "memory");
        }
        __builtin_amdgcn_sched_barrier(0);
        __builtin_amdgcn_s_barrier();
        __builtin_amdgcn_sched_barrier(0);

        // ---- compute from xs[par]: wave handles rows 2*wib, 2*wib+1 of the chunk
        const float* xr0 = xs + par * (ROWS_PER_CHUNK * F_IN) + (wib * 2) * F_IN + q * 128;
        const float* xr1 = xr0 + F_IN;
        float a0 = 0.f, c0 = 0.f, a1 = 0.f, c1 = 0.f;
#pragma unroll
        for (int c = 0; c < 32; ++c) {
            float4 v0 = ((const float4*)xr0)[c];   // broadcast ds_read_b128
            float4 v1 = ((const float4*)xr1)[c];
            a0 = fmaf(v0.x, w[4 * c + 0], a0);
            c0 = fmaf(v0.y, w[4 * c + 1], c0);
            a0 = fmaf(v0.z, w[4 * c + 2], a0);
            c0 = fmaf(v0.w, w[4 * c + 3], c0);
            a1 = fmaf(v1.x, w[4 * c + 0], a1);
            c1 = fmaf(v1.y, w[4 * c + 1], c1);
            a1 = fmaf(v1.z, w[4 * c + 2], a1);
            c1 = fmaf(v1.w, w[4 * c + 3], c1);
        }
        float s0 = a0 + c0, s1 = a1 + c1;
        // reduce across the 4 f-quarters (lanes k, k+16, k+32, k+48)
        s0 += __shfl_xor(s0, 16);
        s0 += __shfl_xor(s0, 32);
        s1 += __shfl_xor(s1, 16);
        s1 += __shfl_xor(s1, 32);
        const int row = chunk * ROWS_PER_CHUNK + wib * 2;
        if (q == 0) {
            float h0 = s0 * dinv[row];
            float h1 = s1 * dinv[row + 1];
            hs1[(size_t)row * HID + k]        = h0;
            acc1[(size_t)row * HID + k]       = h0;
            hs1[(size_t)(row + 1) * HID + k]  = h1;
            acc1[(size_t)(row + 1) * HID + k] = h1;
        }
        __builtin_amdgcn_sched_barrier(0);
        __builtin_amdgcn_s_barrier();   // buf[par] free for the stage 2 iters ahead
        __builtin_amdgcn_sched_barrier(0);
        par ^= 1;
    }
}

// ---------------------------------------------------------------------------
// Layer-1 scatter: 16 threads per edge, one k each.
__global__ void k_scatter1(const int* __restrict__ src, const int* __restrict__ dst,
                           const float* __restrict__ hs1, float* __restrict__ acc1) {
    long long t = (long long)blockIdx.x * blockDim.x + threadIdx.x;
    int e = (int)(t >> 4);
    int k = (int)(t & 15);
    if (e < N_EDGES) {
        int s = src[e], d = dst[e];
        atomicAdd(&acc1[(size_t)d * HID + k], hs1[(size_t)s * HID + k]);
    }
}

// ---------------------------------------------------------------------------
// Per-node middle: z = relu(acc1*dinv + b1); t = z @ W2; ts = t*dinv; acc2 = ts.
__global__ void k_mid(const float* __restrict__ acc1, const float* __restrict__ dinv,
                      const float* __restrict__ b1, const float* __restrict__ W2,
                      float* __restrict__ ts, float* __restrict__ acc2) {
    int i = blockIdx.x * blockDim.x + threadIdx.x;
    if (i >= N_NODES) return;
    float di = dinv[i];
    const float4* a = (const float4*)(acc1 + (size_t)i * HID);
    float t = 0.f;
#pragma unroll
    for (int c = 0; c < 4; ++c) {
        float4 v = a[c];
        float z0 = fmaxf(v.x * di + b1[4 * c + 0], 0.f);
        float z1 = fmaxf(v.y * di + b1[4 * c + 1], 0.f);
        float z2 = fmaxf(v.z * di + b1[4 * c + 2], 0.f);
        float z3 = fmaxf(v.w * di + b1[4 * c + 3], 0.f);
        t += z0 * W2[4 * c + 0] + z1 * W2[4 * c + 1] + z2 * W2[4 * c + 2] + z3 * W2[4 * c + 3];
    }
    float v = t * di;
    ts[i]   = v;
    acc2[i] = v;
}

// ---------------------------------------------------------------------------
// Layer-2 scatter: 1 thread per edge.
__global__ void k_scatter2(const int* __restrict__ src, const int* __restrict__ dst,
                           const float* __restrict__ ts, float* __restrict__ acc2) {
    int e = blockIdx.x * blockDim.x + threadIdx.x;
    if (e < N_EDGES) atomicAdd(&acc2[dst[e]], ts[src[e]]);
}

// ---------------------------------------------------------------------------
__global__ void k_fin(const float* __restrict__ acc2, const float* __restrict__ dinv,
                      const float* __restrict__ b2, float* __restrict__ out) {
    int i = blockIdx.x * blockDim.x + threadIdx.x;
    if (i < N_NODES) {
        float z = acc2[i] * dinv[i] + b2[0];
        out[i] = 1.0f / (1.0f + expf(-z));
    }
}

// ---------------------------------------------------------------------------
extern "C" void kernel_launch(void* const* d_in, const int* in_sizes, int n_in,
                              void* d_out, int out_size, void* d_ws, size_t ws_size,
                              hipStream_t stream) {
    const float* x  = (const float*)d_in[0];
    const float* W1 = (const float*)d_in[1];
    const float* b1 = (const float*)d_in[2];
    const float* W2 = (const float*)d_in[3];
    const float* b2 = (const float*)d_in[4];
    const int*   ei = (const int*)d_in[5];
    const int* src = ei;             // edge_index[0]
    const int* dst = ei + N_EDGES;   // edge_index[1]
    float* out = (float*)d_out;

    char* ws = (char*)d_ws;
    float* acc1 = (float*)ws;                                      // N*HID
    float* hs1  = (float*)(ws + (size_t)N_NODES * HID * 4);        // N*HID
    float* deg  = (float*)(ws + (size_t)2 * N_NODES * HID * 4);    // N
    float* dinv = deg  + N_NODES;                                  // N
    float* ts   = dinv + N_NODES;                                  // N
    float* acc2 = ts   + N_NODES;                                  // N

    hipMemsetAsync(deg, 0, N_NODES * sizeof(float), stream);
    k_deg <<<(N_EDGES + 255) / 256, 256, 0, stream>>>(dst, deg);
    k_dinv<<<(N_NODES + 255) / 256, 256, 0, stream>>>(deg, dinv);
    k_gemm1<<<GEMM1_BLOCKS, 256, 0, stream>>>(x, W1, dinv, hs1, acc1);
    {
        long long tot = (long long)N_EDGES * 16;
        int blocks = (int)((tot + 255) / 256);
        k_scatter1<<<blocks, 256, 0, stream>>>(src, dst, hs1, acc1);
    }
    k_mid <<<(N_NODES + 255) / 256, 256, 0, stream>>>(acc1, dinv, b1, W2, ts, acc2);
    k_scatter2<<<(N_EDGES + 255) / 256, 256, 0, stream>>>(src, dst, ts, acc2);
    k_fin <<<(N_NODES + 255) / 256, 256, 0, stream>>>(acc2, dinv, b2, out);
}

// Round 3
// 762.109 us; speedup vs baseline: 1.0443x; 1.0443x over previous
//
#include <hip/hip_runtime.h>
#include <math.h>

#define N_NODES 100000
#define N_EDGES 3200000
#define F_IN    512
#define HID     16

#define NB ((N_NODES + 255) / 256)          // 391 scan blocks

#define ROWS_PER_CHUNK 8
#define NCHUNK (N_NODES / ROWS_PER_CHUNK)   // 12500 exactly
#define GEMM1_BLOCKS 512

typedef const __attribute__((address_space(1))) void g_void;
typedef __attribute__((address_space(3))) void l_void;

// ---------------------------------------------------------------------------
// In-degree count (int). Self-loop folded in later as +1 in dinv.
__global__ void k_deg(const int* __restrict__ dst, int* __restrict__ deg) {
    int e = blockIdx.x * blockDim.x + threadIdx.x;
    if (e < N_EDGES) atomicAdd(&deg[dst[e]], 1);
}

// Per-block sums of deg for the two-level exclusive scan.
__global__ void k_bsum(const int* __restrict__ deg, int* __restrict__ bsum) {
    int i = blockIdx.x * 256 + threadIdx.x;
    int v = (i < N_NODES) ? deg[i] : 0;
#pragma unroll
    for (int o = 1; o < 64; o <<= 1) v += __shfl_xor(v, o);
    __shared__ int sd[4];
    if ((threadIdx.x & 63) == 0) sd[threadIdx.x >> 6] = v;
    __syncthreads();
    if (threadIdx.x == 0) bsum[blockIdx.x] = sd[0] + sd[1] + sd[2] + sd[3];
}

// Single-block exclusive scan of the 391 block sums.
__global__ void k_scanb(int* __restrict__ bsum) {
    __shared__ int s[512];
    int t = threadIdx.x;
    int v = (t < NB) ? bsum[t] : 0;
    s[t] = v;
    __syncthreads();
    for (int o = 1; o < 512; o <<= 1) {
        int u = (t >= o) ? s[t - o] : 0;
        __syncthreads();
        s[t] += u;
        __syncthreads();
    }
    if (t < NB) bsum[t] = s[t] - v;   // exclusive
}

// rowptr[i] = bsum[blk] + in-block exclusive prefix; cursor copy; dinv.
__global__ void k_rowptr(const int* __restrict__ deg, const int* __restrict__ bsum,
                         int* __restrict__ rowptr, int* __restrict__ cursor,
                         float* __restrict__ dinv) {
    __shared__ int s[256];
    int i = blockIdx.x * 256 + threadIdx.x;
    int v = (i < N_NODES) ? deg[i] : 0;
    s[threadIdx.x] = v;
    __syncthreads();
    for (int o = 1; o < 256; o <<= 1) {
        int u = (threadIdx.x >= o) ? s[threadIdx.x - o] : 0;
        __syncthreads();
        s[threadIdx.x] += u;
        __syncthreads();
    }
    int excl = s[threadIdx.x] - v;
    if (i < N_NODES) {
        int r = bsum[blockIdx.x] + excl;
        rowptr[i] = r;
        cursor[i] = r;
        dinv[i]   = rsqrtf((float)v + 1.0f);
    }
    if (i == 0) rowptr[N_NODES] = N_EDGES;
}

// Counting-sort fill: csr[pos] = src, pos = cursor[dst]++.
__global__ void k_fill(const int* __restrict__ src, const int* __restrict__ dst,
                       int* __restrict__ cursor, int* __restrict__ csr) {
    int e = blockIdx.x * blockDim.x + threadIdx.x;
    if (e < N_EDGES) {
        int p = atomicAdd(&cursor[dst[e]], 1);
        csr[p] = src[e];
    }
}

// ---------------------------------------------------------------------------
// GEMM1: hs1[i][k] = (sum_f x[i][f] * W1[f][k]) * dinv[i]
// 2-phase global_load_lds pipeline, counted vmcnt(4) + raw s_barrier.
__global__ __launch_bounds__(256, 2)
void k_gemm1(const float* __restrict__ x, const float* __restrict__ W1,
             const float* __restrict__ dinv, float* __restrict__ hs1) {
    __shared__ float xs[2 * ROWS_PER_CHUNK * F_IN];   // 2 x 16KB
    const int tid  = threadIdx.x;
    const int lane = tid & 63;
    const int wib  = tid >> 6;     // wave in block (4 waves)
    const int q    = lane >> 4;    // f-quarter
    const int k    = lane & 15;    // output column

    float w[128];
    {
        const float* wp = W1 + (size_t)(q * 128) * HID + k;
#pragma unroll
        for (int j = 0; j < 128; ++j) w[j] = wp[(size_t)j * HID];
    }

    int chunk = blockIdx.x;
    int par = 0;
    {
        const float* gb = x + (size_t)chunk * (ROWS_PER_CHUNK * F_IN);
#pragma unroll
        for (int j = 0; j < 4; ++j) {
            int cidx = j * 4 + wib;
            __builtin_amdgcn_global_load_lds(
                (g_void*)(gb + cidx * 256 + lane * 4),
                (l_void*)(xs + cidx * 256), 16, 0, 0);
        }
    }

    for (; chunk < NCHUNK; chunk += GEMM1_BLOCKS) {
        const int nxt = chunk + GEMM1_BLOCKS;
        if (nxt < NCHUNK) {
            const float* gb = x + (size_t)nxt * (ROWS_PER_CHUNK * F_IN);
            float* lb = xs + (par ^ 1) * (ROWS_PER_CHUNK * F_IN);
#pragma unroll
            for (int j = 0; j < 4; ++j) {
                int cidx = j * 4 + wib;
                __builtin_amdgcn_global_load_lds(
                    (g_void*)(gb + cidx * 256 + lane * 4),
                    (l_void*)(lb + cidx * 256), 16, 0, 0);
            }
            asm volatile("s_waitcnt vmcnt(4)" ::: "memory");
        } else {
            asm volatile("s_waitcnt vmcnt(0)" ::: "memory");
        }
        __builtin_amdgcn_sched_barrier(0);
        __builtin_amdgcn_s_barrier();
        __builtin_amdgcn_sched_barrier(0);

        const float* xr0 = xs + par * (ROWS_PER_CHUNK * F_IN) + (wib * 2) * F_IN + q * 128;
        const float* xr1 = xr0 + F_IN;
        float a0 = 0.f, c0 = 0.f, a1 = 0.f, c1 = 0.f;
#pragma unroll
        for (int c = 0; c < 32; ++c) {
            float4 v0 = ((const float4*)xr0)[c];
            float4 v1 = ((const float4*)xr1)[c];
            a0 = fmaf(v0.x, w[4 * c + 0], a0);
            c0 = fmaf(v0.y, w[4 * c + 1], c0);
            a0 = fmaf(v0.z, w[4 * c + 2], a0);
            c0 = fmaf(v0.w, w[4 * c + 3], c0);
            a1 = fmaf(v1.x, w[4 * c + 0], a1);
            c1 = fmaf(v1.y, w[4 * c + 1], c1);
            a1 = fmaf(v1.z, w[4 * c + 2], a1);
            c1 = fmaf(v1.w, w[4 * c + 3], c1);
        }
        float s0 = a0 + c0, s1 = a1 + c1;
        s0 += __shfl_xor(s0, 16);
        s0 += __shfl_xor(s0, 32);
        s1 += __shfl_xor(s1, 16);
        s1 += __shfl_xor(s1, 32);
        const int row = chunk * ROWS_PER_CHUNK + wib * 2;
        if (q == 0) {
            hs1[(size_t)row * HID + k]       = s0 * dinv[row];
            hs1[(size_t)(row + 1) * HID + k] = s1 * dinv[row + 1];
        }
        __builtin_amdgcn_sched_barrier(0);
        __builtin_amdgcn_s_barrier();
        __builtin_amdgcn_sched_barrier(0);
        par ^= 1;
    }
}

// ---------------------------------------------------------------------------
// Layer-1 aggregate + middle, fused. 16 lanes per node (lane = feature k).
// s_k = hs1[i][k] + sum_j hs1[csr[j]][k]  (each gather: 16 lanes x 4B = one 64B line)
// z_k = relu(s_k * dinv[i] + b1[k]);  t = sum_k z_k * W2[k];  ts[i] = t * dinv[i].
__global__ void k_agg1mid(const float* __restrict__ hs1, const int* __restrict__ rowptr,
                          const int* __restrict__ csr, const float* __restrict__ dinv,
                          const float* __restrict__ b1, const float* __restrict__ W2,
                          float* __restrict__ ts) {
    int t = blockIdx.x * blockDim.x + threadIdx.x;
    int g = t >> 4;          // node
    int k = t & 15;          // feature
    if (g >= N_NODES) return;
    int beg = rowptr[g], end = rowptr[g + 1];
    float s0 = hs1[(size_t)g * HID + k];   // self-loop
    float s1 = 0.f;
    int e = beg;
    for (; e + 1 < end; e += 2) {
        int j0 = csr[e], j1 = csr[e + 1];
        s0 += hs1[(size_t)j0 * HID + k];
        s1 += hs1[(size_t)j1 * HID + k];
    }
    if (e < end) s0 += hs1[(size_t)csr[e] * HID + k];
    float di = dinv[g];
    float z = fmaxf((s0 + s1) * di + b1[k], 0.f) * W2[k];
    z += __shfl_xor(z, 1, 16);
    z += __shfl_xor(z, 2, 16);
    z += __shfl_xor(z, 4, 16);
    z += __shfl_xor(z, 8, 16);
    if (k == 0) ts[g] = z * di;
}

// ---------------------------------------------------------------------------
// Layer-2 aggregate + sigmoid, fused. 16 lanes per node, edges strided over lanes.
__global__ void k_agg2fin(const float* __restrict__ ts, const int* __restrict__ rowptr,
                          const int* __restrict__ csr, const float* __restrict__ dinv,
                          const float* __restrict__ b2, float* __restrict__ out) {
    int t = blockIdx.x * blockDim.x + threadIdx.x;
    int g = t >> 4;
    int l = t & 15;
    if (g >= N_NODES) return;
    int beg = rowptr[g], end = rowptr[g + 1];
    float s = (l == 0) ? ts[g] : 0.f;      // self-loop
    for (int e = beg + l; e < end; e += 16) s += ts[csr[e]];
    s += __shfl_xor(s, 1, 16);
    s += __shfl_xor(s, 2, 16);
    s += __shfl_xor(s, 4, 16);
    s += __shfl_xor(s, 8, 16);
    if (l == 0) {
        float z = s * dinv[g] + b2[0];
        out[g] = 1.0f / (1.0f + expf(-z));
    }
}

// ---------------------------------------------------------------------------
extern "C" void kernel_launch(void* const* d_in, const int* in_sizes, int n_in,
                              void* d_out, int out_size, void* d_ws, size_t ws_size,
                              hipStream_t stream) {
    const float* x  = (const float*)d_in[0];
    const float* W1 = (const float*)d_in[1];
    const float* b1 = (const float*)d_in[2];
    const float* W2 = (const float*)d_in[3];
    const float* b2 = (const float*)d_in[4];
    const int*   ei = (const int*)d_in[5];
    const int* src = ei;             // edge_index[0]
    const int* dst = ei + N_EDGES;   // edge_index[1]
    float* out = (float*)d_out;

    char* ws = (char*)d_ws;
    float* hs1   = (float*)ws;                       // N*HID f32
    int*   deg    = (int*)(hs1 + (size_t)N_NODES * HID);
    int*   rowptr = deg + N_NODES;                   // N+1
    int*   cursor = rowptr + N_NODES + 1;            // N
    float* dinv   = (float*)(cursor + N_NODES);      // N
    float* ts     = dinv + N_NODES;                  // N
    int*   bsum   = (int*)(ts + N_NODES);            // NB (pad 512)
    int*   csr    = bsum + 512;                      // E

    hipMemsetAsync(deg, 0, N_NODES * sizeof(int), stream);
    k_deg   <<<(N_EDGES + 255) / 256, 256, 0, stream>>>(dst, deg);
    k_bsum  <<<NB, 256, 0, stream>>>(deg, bsum);
    k_scanb <<<1, 512, 0, stream>>>(bsum);
    k_rowptr<<<NB, 256, 0, stream>>>(deg, bsum, rowptr, cursor, dinv);
    k_fill  <<<(N_EDGES + 255) / 256, 256, 0, stream>>>(src, dst, cursor, csr);
    k_gemm1 <<<GEMM1_BLOCKS, 256, 0, stream>>>(x, W1, dinv, hs1);
    {
        long long tot = (long long)N_NODES * 16;
        int blocks = (int)((tot + 255) / 256);
        k_agg1mid<<<blocks, 256, 0, stream>>>(hs1, rowptr, csr, dinv, b1, W2, ts);
        k_agg2fin<<<blocks, 256, 0, stream>>>(ts, rowptr, csr, dinv, b2, out);
    }
}